// Round 5
// baseline (459.420 us; speedup 1.0000x reference)
//
#include <hip/hip_runtime.h>
#include <stdint.h>

// Batched Viterbi decode: B=8192, T=512, K=12.
// r5 = r4 with ONE change: the argmax select chain (11 serially-dependent
// vcc cmp/cndmask links per column -> ~33 serialized vcc round-trips/step,
// the hypothesized 50-75% stall at 1 wave/SIMD) is replaced by 12
// INDEPENDENT compares + a parallel integer min3 tree (first-index tie
// semantics preserved exactly: min index among values equal to the max).
// Everything else is byte-identical to r4 (quad_perm exchange, zero-LDS
// direct-global emissions with 8-step lookahead, ushort bp records, proven
// backtrack mux).

namespace {

constexpr int kB = 8192;
constexpr int kT = 512;
constexpr int kK = 12;

typedef float vf3 __attribute__((ext_vector_type(3)));

__device__ __forceinline__ int imin(int a, int b) { return a < b ? a : b; }

template <int CTRL>
__device__ __forceinline__ float dppb(float x) {
    // quad_perm broadcast of quad-lane q: CTRL = q * 0x55  [HW-verified r0/r4]
    return __int_as_float(__builtin_amdgcn_update_dpp(
        0, __float_as_int(x), CTRL, 0xf, 0xf, true));
}

__global__ __launch_bounds__(64) void viterbi_fused(
    const float* __restrict__ logits,   // [B, T, K]
    const float* __restrict__ trans,    // [K, K]
    float* __restrict__ out,            // [B] scores + [B*T] paths (floats)
    uint16_t* __restrict__ bp)          // [B][511][4] ushorts (3 nibbles each)
{
    const int ln = threadIdx.x;     // 0..63
    const int qd = ln >> 2;         // row within wave: 0..15
    const int c  = ln & 3;          // quad lane = column group
    const int b  = blockIdx.x * 16 + qd;
    const int j0 = 3 * c;           // this lane's columns j0..j0+2

    // transition columns j0, j0+1, j0+2 (36 regs)
    float TA[12], TB[12], TC[12];
#pragma unroll
    for (int i = 0; i < 12; ++i) {
        TA[i] = trans[i * kK + j0];
        TB[i] = trans[i * kK + j0 + 1];
        TC[i] = trans[i * kK + j0 + 2];
    }

    uint16_t* __restrict__ bps = bp + (size_t)b * 511 * 4 + c;

    // per-lane emission pointer: em[b][t][j0..j0+2]
    const float* __restrict__ gem = logits + (size_t)b * (kT * kK) + j0;

    // direct global load of this lane's 3 emission floats at step t
    auto ld = [&](int t) -> vf3 {
        const int tc = (t < kT) ? t : (kT - 1);
        vf3 v;
        __builtin_memcpy(&v, gem + (size_t)tc * kK, 12);   // dwordx3, 4B-align
        return v;
    };

    // trellis t=0 in n0..n2 (this lane's 3 columns)
    vf3 iv = ld(0);
    float n0 = iv.x, n1 = iv.y, n2 = iv.z;

    // 8-step emission lookahead in registers
    vf3 e0 = ld(1), e1 = ld(2), e2 = ld(3), e3 = ld(4);
    vf3 e4 = ld(5), e5 = ld(6), e6 = ld(7), e7 = ld(8);

    // prev[3q+r] = quad-lane q's n_r   [HW-verified r0/r4]
#define GATHER()                                                             \
    const float p0 = dppb<0x00>(n0), p1 = dppb<0x00>(n1), p2 = dppb<0x00>(n2);\
    const float p3 = dppb<0x55>(n0), p4 = dppb<0x55>(n1), p5 = dppb<0x55>(n2);\
    const float p6 = dppb<0xAA>(n0), p7 = dppb<0xAA>(n1), p8 = dppb<0xAA>(n2);\
    const float p9 = dppb<0xFF>(n0), p10 = dppb<0xFF>(n1), p11 = dppb<0xFF>(n2)

    // one output column: 12 adds, max3 tree, then argmax as 12 INDEPENDENT
    // compares + integer min3 tree (exact first-index ties; no serial vcc
    // chain -- every cmp/cndmask pair is independent, min tree is depth 3)
#define COLX(Tc, EMITc, NOUT, BIOUT) do {                                    \
    const float x0 = p0 + Tc[0],  x1 = p1 + Tc[1],  x2 = p2 + Tc[2];         \
    const float x3 = p3 + Tc[3],  x4 = p4 + Tc[4],  x5 = p5 + Tc[5];         \
    const float x6 = p6 + Tc[6],  x7 = p7 + Tc[7],  x8 = p8 + Tc[8];         \
    const float x9 = p9 + Tc[9],  x10 = p10 + Tc[10], x11 = p11 + Tc[11];    \
    const float mA = fmaxf(fmaxf(x0, x1), x2);                               \
    const float mB = fmaxf(fmaxf(x3, x4), x5);                               \
    const float mC = fmaxf(fmaxf(x6, x7), x8);                               \
    const float mD = fmaxf(fmaxf(x9, x10), x11);                             \
    const float best = fmaxf(fmaxf(mA, mB), fmaxf(mC, mD));                  \
    const int c0_ = (x0 == best) ? 0 : 63;                                   \
    const int c1_ = (x1 == best) ? 1 : 63;                                   \
    const int c2_ = (x2 == best) ? 2 : 63;                                   \
    const int c3_ = (x3 == best) ? 3 : 63;                                   \
    const int c4_ = (x4 == best) ? 4 : 63;                                   \
    const int c5_ = (x5 == best) ? 5 : 63;                                   \
    const int c6_ = (x6 == best) ? 6 : 63;                                   \
    const int c7_ = (x7 == best) ? 7 : 63;                                   \
    const int c8_ = (x8 == best) ? 8 : 63;                                   \
    const int c9_ = (x9 == best) ? 9 : 63;                                   \
    const int c10_ = (x10 == best) ? 10 : 63;                                \
    const int c11_ = (x11 == best) ? 11 : 63;                                \
    const int t0_ = imin(imin(c0_, c1_), c2_);                               \
    const int t1_ = imin(imin(c3_, c4_), c5_);                               \
    const int t2_ = imin(imin(c6_, c7_), c8_);                               \
    const int t3_ = imin(imin(c9_, c10_), c11_);                             \
    const int bi = imin(imin(t0_, t1_), imin(t2_, t3_));                     \
    NOUT = best + (EMITc);  BIOUT = bi;                                      \
} while (0)

#define STEP(TT, EV) do {                                                    \
    GATHER();                                                                \
    float q0_, q1_, q2_; int b0_, b1_, b2_;                                  \
    COLX(TA, (EV).x, q0_, b0_);                                              \
    COLX(TB, (EV).y, q1_, b1_);                                              \
    COLX(TC, (EV).z, q2_, b2_);                                              \
    n0 = q0_; n1 = q1_; n2 = q2_;                                            \
    const uint32_t w_ = (uint32_t)b0_ | ((uint32_t)b1_ << 4)                 \
                        | ((uint32_t)b2_ << 8);                              \
    bps[(size_t)((TT) - 1) * 4] = (uint16_t)w_;                              \
} while (0)

    // main: t = 1..504 in 63 sub-blocks of 8 (no waits, no barriers)
#pragma unroll 1
    for (int sb = 0; sb < 63; ++sb) {
        const int tb = 8 * sb + 1;

        const vf3 f0 = ld(tb + 8),  f1 = ld(tb + 9);
        const vf3 f2 = ld(tb + 10), f3 = ld(tb + 11);
        const vf3 f4 = ld(tb + 12), f5 = ld(tb + 13);
        const vf3 f6 = ld(tb + 14), f7 = ld(tb + 15);

        STEP(tb + 0, e0); STEP(tb + 1, e1); STEP(tb + 2, e2); STEP(tb + 3, e3);
        STEP(tb + 4, e4); STEP(tb + 5, e5); STEP(tb + 6, e6); STEP(tb + 7, e7);

        e0 = f0; e1 = f1; e2 = f2; e3 = f3;
        e4 = f4; e5 = f5; e6 = f6; e7 = f7;
    }

    // tail: t = 505..511 (e0..e6 hold em[505..511])
    STEP(505, e0); STEP(506, e1); STEP(507, e2); STEP(508, e3);
    STEP(509, e4); STEP(510, e5); STEP(511, e6);

#undef STEP

    // final 12-way max + first-index argmax (all 4 quad lanes agree)
    float best;
    int last;
    {
        GATHER();
        const float mA = fmaxf(fmaxf(p0, p1), p2);
        const float mB = fmaxf(fmaxf(p3, p4), p5);
        const float mC = fmaxf(fmaxf(p6, p7), p8);
        const float mD = fmaxf(fmaxf(p9, p10), p11);
        best = fmaxf(fmaxf(mA, mB), fmaxf(mC, mD));
        const int c0_ = (p0 == best) ? 0 : 63;
        const int c1_ = (p1 == best) ? 1 : 63;
        const int c2_ = (p2 == best) ? 2 : 63;
        const int c3_ = (p3 == best) ? 3 : 63;
        const int c4_ = (p4 == best) ? 4 : 63;
        const int c5_ = (p5 == best) ? 5 : 63;
        const int c6_ = (p6 == best) ? 6 : 63;
        const int c7_ = (p7 == best) ? 7 : 63;
        const int c8_ = (p8 == best) ? 8 : 63;
        const int c9_ = (p9 == best) ? 9 : 63;
        const int c10_ = (p10 == best) ? 10 : 63;
        const int c11_ = (p11 == best) ? 11 : 63;
        const int t0_ = imin(imin(c0_, c1_), c2_);
        const int t1_ = imin(imin(c3_, c4_), c5_);
        const int t2_ = imin(imin(c6_, c7_), c8_);
        const int t3_ = imin(imin(c9_, c10_), c11_);
        last = imin(imin(t0_, t1_), imin(t2_, t3_));
    }
#undef GATHER
#undef COLX

    __syncthreads();   // drain backpointer stores before same-wave readback

    // Backtrack (r0/r4-proven): one lane per row reads its ushort records and
    // follows the chain with an in-register nibble mux.
    if (c == 0) {
        out[b] = best;
        float* __restrict__ paths = out + kB + (size_t)b * kT;
        paths[kT - 1] = (float)last;

        int tag = last;
        const uint2* __restrict__ rec = (const uint2*)(bp + (size_t)b * 511 * 4);
#pragma unroll 4
        for (int s = 510; s >= 0; --s) {
            const uint2 q = rec[s];
            const int d3 = (tag * 11) >> 5;        // tag / 3  (exact for 0..15)
            const int rm = tag - 3 * d3;           // tag % 3
            const uint32_t dw = (d3 & 2) ? q.y : q.x;
            const int sh = ((d3 & 1) << 4) + (rm << 2);
            tag = (int)((dw >> sh) & 0xF);
            paths[s] = (float)tag;
        }
    }
}

} // namespace

extern "C" void kernel_launch(void* const* d_in, const int* in_sizes, int n_in,
                              void* d_out, int out_size, void* d_ws, size_t ws_size,
                              hipStream_t stream) {
    const float* logits = (const float*)d_in[0];   // [8192, 512, 12] f32
    const float* trans  = (const float*)d_in[1];   // [12, 12] f32
    float* out = (float*)d_out;
    uint16_t* bp = (uint16_t*)d_ws;                // 8192*511*4*2 = 33.5 MB

    const int threads = 64;                        // 1 wave, 16 rows
    const int blocks = kB / 16;                    // 512 blocks
    viterbi_fused<<<blocks, threads, 0, stream>>>(logits, trans, out, bp);
}